// Round 2
// baseline (234.582 us; speedup 1.0000x reference)
//
#include <hip/hip_runtime.h>

#define Bn 16
#define Cn 64
#define Hn 128
#define Wn 128
#define HWn (Hn * Wn)

__device__ __forceinline__ float wave_reduce64(float v) {
    #pragma unroll
    for (int m = 1; m < 64; m <<= 1)
        v += __shfl_xor(v, m, 64);
    return v;
}

// ---------------------------------------------------------------------------
// Kernel 1: generate per-(batch,channel) 3x3 kernels + transpose Wc.
//   hid[b,i] = lrelu(sum_j d[b,j] * Wk1[i,j])            (16,64)
//   kern[b,o] = sum_j hid[b,j] * Wk2[o,j], o in [0,576)  (16,576)
// All global loads coalesced (lane j reads element j of a weight row);
// one wave-reduction per output, unroll-4 for ILP across the shfl chains.
// ---------------------------------------------------------------------------
__global__ __launch_bounds__(256)
void gen_kern2(const float* __restrict__ d,
               const float* __restrict__ Wk1,
               const float* __restrict__ Wk2,
               const float* __restrict__ Wc,
               float* __restrict__ kern_out,   // ws: [16][576]
               float* __restrict__ WcT) {      // ws: [64][64]  WcT[c][o]=Wc[o][c]
    const int b    = blockIdx.x;        // 16 blocks
    const int lane = threadIdx.x & 63;
    const int wv   = threadIdx.x >> 6;  // 0..3
    __shared__ float hid_s[64];

    const float dj = d[b * 64 + lane];

    // hid: wave wv computes hid[wv*16 .. wv*16+15]
    #pragma unroll 4
    for (int i = 0; i < 16; ++i) {
        const int o = wv * 16 + i;
        float p = Wk1[o * 64 + lane] * dj;   // coalesced
        p = wave_reduce64(p);
        if (lane == 0) hid_s[o] = (p >= 0.f) ? p : 0.1f * p;
    }
    __syncthreads();
    const float hj = hid_s[lane];

    // kern: wave wv computes o = wv*144 .. wv*144+143
    #pragma unroll 4
    for (int i = 0; i < 144; ++i) {
        const int o = wv * 144 + i;
        float p = Wk2[o * 64 + lane] * hj;   // coalesced
        p = wave_reduce64(p);
        if (lane == 0) kern_out[b * 576 + o] = p;
    }

    // Wc transpose, done once (block 0): WcT[c*64+o] = Wc[o*64+c]
    if (b == 0) {
        for (int idx = threadIdx.x; idx < 64 * 64; idx += 256) {
            const int o = idx >> 6, c = idx & 63;
            WcT[c * 64 + o] = Wc[idx];
        }
    }
}

// ---------------------------------------------------------------------------
// Kernel 2: fused dynamic depthwise 3x3 (SAME) -> lrelu -> 1x1 conv + bias.
// One thread per output pixel; 64 fp32 accumulators (AGPR-backed).
// Channel loop is software-pipelined: prefetch c+1's 9 taps into `nxt`
// while the 64 accumulate-FMAs for channel c execute, so the ~200cy L2
// tap latency is hidden behind VALU work.
// kern taps and WcT rows are wave-uniform -> scalar loads (WcT row is 64
// consecutive floats -> 4x s_load_dwordx16 per channel).
// ---------------------------------------------------------------------------
__global__ __launch_bounds__(256, 4)
void da_main(const float* __restrict__ x,
             const float* __restrict__ kern,
             const float* __restrict__ WcT,
             const float* __restrict__ bc,
             float* __restrict__ out) {
    const int w = (blockIdx.x << 6) + (threadIdx.x & 63);
    const int h = (blockIdx.y << 2) + (threadIdx.x >> 6);
    const int b = blockIdx.z;

    const float* __restrict__ xb = x + (size_t)b * Cn * HWn;
    const float* __restrict__ kb = kern + b * 576;

    // Clamped tap offsets (always in-bounds) + validity masks
    int rofs[3]; bool rok[3];
    int cofs[3]; bool cok[3];
    #pragma unroll
    for (int i = 0; i < 3; ++i) {
        const int hh = h + i - 1;
        rok[i]  = (hh >= 0) && (hh < Hn);
        rofs[i] = (hh < 0 ? 0 : (hh >= Hn ? Hn - 1 : hh)) * Wn;
        const int ww = w + i - 1;
        cok[i]  = (ww >= 0) && (ww < Wn);
        cofs[i] = (ww < 0 ? 0 : (ww >= Wn ? Wn - 1 : ww));
    }
    int  off[9];
    bool msk[9];
    #pragma unroll
    for (int r = 0; r < 3; ++r)
        #pragma unroll
        for (int c2 = 0; c2 < 3; ++c2) {
            off[r * 3 + c2] = rofs[r] + cofs[c2];
            msk[r * 3 + c2] = rok[r] && cok[c2];
        }

    float acc[64];
    #pragma unroll
    for (int o = 0; o < 64; ++o) acc[o] = bc[o];

    // Prologue: load channel 0 taps
    float cur[9];
    #pragma unroll
    for (int i = 0; i < 9; ++i) cur[i] = xb[off[i]];

    #pragma unroll 2
    for (int c = 0; c < Cn; ++c) {
        // Prefetch next channel's taps (c=63 re-fetches itself; harmless)
        const float* __restrict__ xn = xb + (c + 1 < Cn ? c + 1 : c) * HWn;
        float nxt[9];
        #pragma unroll
        for (int i = 0; i < 9; ++i) nxt[i] = xn[off[i]];

        // Depthwise 3x3 for channel c (taps kb wave-uniform -> SGPRs)
        float v = 0.f;
        #pragma unroll
        for (int i = 0; i < 9; ++i)
            v += (msk[i] ? cur[i] : 0.f) * kb[c * 9 + i];
        v = (v >= 0.f) ? v : 0.1f * v;

        // 1x1 conv: WcT[c][o] wave-uniform contiguous -> s_load_dwordx16
        const float* __restrict__ wcc = WcT + (c << 6);
        #pragma unroll
        for (int o = 0; o < 64; ++o)
            acc[o] += v * wcc[o];

        #pragma unroll
        for (int i = 0; i < 9; ++i) cur[i] = nxt[i];
    }

    float* __restrict__ ob = out + (size_t)b * Cn * HWn + h * Wn + w;
    #pragma unroll
    for (int o = 0; o < 64; ++o)
        ob[(size_t)o * HWn] = acc[o];
}

// ---------------------------------------------------------------------------
extern "C" void kernel_launch(void* const* d_in, const int* in_sizes, int n_in,
                              void* d_out, int out_size, void* d_ws, size_t ws_size,
                              hipStream_t stream) {
    const float* x   = (const float*)d_in[0];
    const float* d   = (const float*)d_in[1];
    const float* Wk1 = (const float*)d_in[2];
    const float* Wk2 = (const float*)d_in[3];
    const float* Wc  = (const float*)d_in[4];
    const float* bc  = (const float*)d_in[5];
    float* out  = (float*)d_out;
    float* kern = (float*)d_ws;                  // 16*576 floats
    float* WcT  = (float*)d_ws + Bn * 576;       // 64*64 floats

    gen_kern2<<<dim3(Bn), dim3(256), 0, stream>>>(d, Wk1, Wk2, Wc, kern, WcT);
    da_main<<<dim3(Wn / 64, Hn / 4, Bn), dim3(256), 0, stream>>>(x, kern, WcT, bc, out);
}